// Round 7
// baseline (126.388 us; speedup 1.0000x reference)
//
#include <hip/hip_runtime.h>
#include <hip/hip_fp16.h>

typedef __attribute__((ext_vector_type(8))) _Float16 half8;
typedef __attribute__((ext_vector_type(4))) float f32x4;
typedef __attribute__((ext_vector_type(4))) unsigned int uint4v;

#define HGT 2048
#define WID 2048
#define NPTS 1000000
#define NTILES 3907           // ceil(1e6 / 256 points per block)
#define WBYTES 44096          // 42 frags * 1024 B + 1088 B biases
#define BIAS_OFF 43008

// Feature-slot permutation maps: producer c-slot feeding k-slot k (register-renaming transpose).
__device__ __host__ inline int c64map(int k){   // 64-feature producer
  return 16*(k>>5) + 32*((k&7)>>2) + 4*((k>>3)&3) + (k&3);
}
__device__ __host__ inline int c128map(int k){  // 128-feature producer
  return 16*(k>>5) + 64*((k&7)>>2) + 4*((k>>3)&3) + (k&3);
}

// ---------------- prepack: weights -> f16 A-fragment order in d_ws ----------------
__global__ void prepack_kernel(const float* __restrict__ W1, const float* __restrict__ b1,
                               const float* __restrict__ W2, const float* __restrict__ b2,
                               const float* __restrict__ W3, const float* __restrict__ b3,
                               const float* __restrict__ W4, const float* __restrict__ b4,
                               unsigned short* __restrict__ packed){
  int tid = blockIdx.x*256 + threadIdx.x;
  if (tid < 42*64) {
    int f = tid >> 6, l = tid & 63;
    int fr = l & 15, kg = l >> 4;
    int layer, mt, kk;
    if (f < 8)       { layer=1; mt=f>>1;      kk=f&1; }
    else if (f < 24) { layer=2; mt=(f-8)>>1;  kk=(f-8)&1; }
    else if (f < 40) { layer=3; mt=(f-24)>>2; kk=(f-24)&3; }
    else             { layer=4; mt=0;         kk=f-40; }
    unsigned short v16[8];
    #pragma unroll
    for (int e=0;e<8;e++){
      int k = kk*32 + kg*8 + e;
      int fout = mt*16 + fr;
      float v = 0.0f;
      if (layer==1) {
        if (k < 36)      { v = W1[((k>>2)*12 + (k&3))*64 + fout]; }
        else if (k < 42) { float s=0.f; for (int p=0;p<9;p++) s += W1[(p*12+4+(k-36))*64 + fout]; v=s; }
        else if (k < 44) { float s=0.f; for (int p=0;p<9;p++) s += W1[(p*12+10+(k-42))*64 + fout]; v=s; }
      } else if (layer==2) { v = W2[c64map(k)*128 + fout]; }
      else if (layer==3)   { v = W3[c128map(k)*64 + fout]; }
      else                 { v = (fr < 4) ? W4[c64map(k)*4 + fr] : 0.0f; }
      v16[e] = __half_as_ushort(__float2half(v));
    }
    unsigned short* dst = packed + (size_t)f*512 + (size_t)l*8;
    #pragma unroll
    for (int e=0;e<8;e++) dst[e] = v16[e];
  }
  int bt = tid - 42*64;
  if (bt >= 0 && bt < 272) {
    float v;
    if (bt < 64)       v = b1[bt];
    else if (bt < 192) v = b2[bt-64];
    else if (bt < 256) v = b3[bt-192];
    else               v = (bt-256 < 4) ? b4[bt-256] : 0.0f;
    ((float*)((char*)packed + BIAS_OFF))[bt] = v;
  }
}

// ---------------- helpers ----------------
__device__ inline unsigned pkf(float a, float b){
  return __builtin_bit_cast(unsigned, __builtin_amdgcn_cvt_pkrtz(a, b));
}
// rational GELU (plain C, deterministic codegen): gelu(x) = x*(0.5 + xc*r(xc^2)),
// xc = clamp(x,-4,4) (compiler fuses to v_med3_f32); r(s) = (p0+p1 s+p2 s^2)/(1+q1 s+q2 s^2)
// interpolates exact Phi at s={0,1,4,9,16}; |err(r)| <~ 2e-4 -> |gelu err| <~ 2e-3.
// For |x|>4 Phi saturates (1-Phi(4)=3.2e-5) -> gelu ~= x automatically.
__device__ inline float gelu1(float x){
  const float xc = fminf(fmaxf(x, -4.0f), 4.0f);
  const float s  = xc*xc;
  const float num = __builtin_fmaf(__builtin_fmaf(0.0026758f, s, 0.0986155f), s, 0.3989423f);
  const float den = __builtin_fmaf(__builtin_fmaf(0.0535340f, s, 0.4119460f), s, 1.0f);
  return __builtin_fmaf(x*xc*__builtin_amdgcn_rcpf(den), num, 0.5f*x);
}
__device__ inline unsigned gelu2_v(float a, float b){
  return pkf(gelu1(a), gelu1(b));
}
__device__ inline float fast_sigmoid(float x){
  return __builtin_amdgcn_rcpf(1.0f + __builtin_amdgcn_exp2f(-1.442695041f*x));
}
__device__ inline half8 mk8(uint2 a, uint2 b){
  uint4v t; t.x = a.x; t.y = a.y; t.z = b.x; t.w = b.y;
  return __builtin_bit_cast(half8, t);
}

// One layer for TWO 16-point groups sharing each weight-frag read (J=2).
// C-in = bias (free bias add). Output u[mt] = packed f16 pairs (j01, j23).
template<int MT,int KT,int FB,int BO>
__device__ inline void layer2(const half8* __restrict__ Wfrag, const float* __restrict__ bias,
                              const half8* bxa, const half8* bxb,
                              uint2* ua, uint2* ub, int lane, int g){
  #pragma unroll
  for (int mt=0; mt<MT; mt++){
    const f32x4 bv = *(const f32x4*)(bias + BO + mt*16 + g*4);
    f32x4 a = bv, b = bv;
    #pragma unroll
    for (int kk=0; kk<KT; kk++){
      const half8 w = Wfrag[(FB + mt*KT + kk)*64 + lane];
      a = __builtin_amdgcn_mfma_f32_16x16x32_f16(w, bxa[kk], a, 0,0,0);
      b = __builtin_amdgcn_mfma_f32_16x16x32_f16(w, bxb[kk], b, 0,0,0);
    }
    ua[mt].x = gelu2_v(a[0], a[1]); ua[mt].y = gelu2_v(a[2], a[3]);
    ub[mt].x = gelu2_v(b[0], b[1]); ub[mt].y = gelu2_v(b[2], b[3]);
  }
}

// ---------------- main fused kernel: registers-only dataflow ----------------
__global__ __launch_bounds__(512, 6)
void decoder_kernel(const float* __restrict__ latent, const int* __restrict__ raw_pos,
                    const float* __restrict__ control, const unsigned short* __restrict__ packed,
                    float* __restrict__ out){
  __shared__ __attribute__((aligned(16))) char smem[WBYTES];
  const int tid = threadIdx.x;
  {
    const f32x4* src = (const f32x4*)packed;
    f32x4* dst = (f32x4*)smem;
    for (int i = tid; i < WBYTES/16; i += 512) dst[i] = src[i];
  }
  __syncthreads();

  const half8* Wfrag = (const half8*)smem;
  const float* bias  = (const float*)(smem + BIAS_OFF);
  const int wave = tid >> 6, lane = tid & 63;
  const int nlo = lane & 15, g = lane >> 4;
  // per-lane gather offsets for pixels 2g, 2g+1 (dx = p%3-1, dy = p/3-1)
  const int pA = g*2, pB = g*2+1;
  const int qA = (pA>=3) + (pA>=6), qB = (pB>=3) + (pB>=6);
  const int dyA = qA-1, dxA = pA-3*qA-1;
  const int dyB = qB-1, dxB = pB-3*qB-1;

  const int tile = blockIdx.x;
  const int R0 = tile*256 + wave*32;
  if (R0 >= NPTS) return;

  // ---------- build L1 B-frags for two point groups, per-lane direct gather ----------
  half8 bx[2][2];
  #pragma unroll
  for (int jj=0; jj<2; jj++){
    const int prow = R0 + jj*16 + nlo;
    const int2 xy = ((const int2*)raw_pos)[prow];
    const int exA = min(max(xy.x + dxA, 0), WID-1);
    const int eyA = min(max(xy.y + dyA, 0), HGT-1);
    const int exB = min(max(xy.x + dxB, 0), WID-1);
    const int eyB = min(max(xy.y + dyB, 0), HGT-1);
    const f32x4 lA = *(const f32x4*)(latent + ((size_t)eyA*WID + exA)*4);
    const f32x4 lB = *(const f32x4*)(latent + ((size_t)eyB*WID + exB)*4);
    uint4v f0;
    f0.x = pkf(lA[0], lA[1]); f0.y = pkf(lA[2], lA[3]);
    f0.z = pkf(lB[0], lB[1]); f0.w = pkf(lB[2], lB[3]);
    bx[jj][0] = __builtin_bit_cast(half8, f0);

    const float xs = (float)xy.x * (1.0f/WID), ys = (float)xy.y * (1.0f/HGT);
    const float sx = __builtin_amdgcn_sinf(xs), cx = __builtin_amdgcn_cosf(xs);
    const float sy = __builtin_amdgcn_sinf(ys), cy = __builtin_amdgcn_cosf(ys);
    uint4v f1; f1.x = 0u; f1.y = 0u; f1.z = 0u; f1.w = 0u;
    if (g == 0){
      const int ex8 = min(xy.x + 1, WID-1), ey8 = min(xy.y + 1, HGT-1);
      const f32x4 l8 = *(const f32x4*)(latent + ((size_t)ey8*WID + ex8)*4);
      f1.x = pkf(l8[0], l8[1]); f1.y = pkf(l8[2], l8[3]);
      f1.z = pkf(xs, ys); f1.w = pkf(sx, cx);
    } else if (g == 1){
      const float2 ct = ((const float2*)control)[prow];
      f1.x = pkf(sy, cy); f1.y = pkf(ct.x, ct.y);
    }
    bx[jj][1] = __builtin_bit_cast(half8, f1);
  }

  // ---------- MLP chain, activations live entirely in registers ----------
  uint2 u0[8], u1[8];
  half8 ha[4], hb[4];
  layer2<4,2,0,0>(Wfrag, bias, bx[0], bx[1], u0, u1, lane, g);          // L1: 64->64
  ha[0]=mk8(u0[0],u0[2]); ha[1]=mk8(u0[1],u0[3]);
  hb[0]=mk8(u1[0],u1[2]); hb[1]=mk8(u1[1],u1[3]);
  layer2<8,2,8,64>(Wfrag, bias, ha, hb, u0, u1, lane, g);               // L2: 64->128
  ha[0]=mk8(u0[0],u0[4]); ha[1]=mk8(u0[1],u0[5]);
  ha[2]=mk8(u0[2],u0[6]); ha[3]=mk8(u0[3],u0[7]);
  hb[0]=mk8(u1[0],u1[4]); hb[1]=mk8(u1[1],u1[5]);
  hb[2]=mk8(u1[2],u1[6]); hb[3]=mk8(u1[3],u1[7]);
  layer2<4,4,24,192>(Wfrag, bias, ha, hb, u0, u1, lane, g);             // L3: 128->64
  ha[0]=mk8(u0[0],u0[2]); ha[1]=mk8(u0[1],u0[3]);
  hb[0]=mk8(u1[0],u1[2]); hb[1]=mk8(u1[1],u1[3]);

  // ---------- L4: 64->4 + sigmoid ----------
  const f32x4 bv4 = *(const f32x4*)(bias + 256 + g*4);
  f32x4 a = bv4, b = bv4;
  #pragma unroll
  for (int kk=0; kk<2; kk++){
    const half8 w = Wfrag[(40+kk)*64 + lane];
    a = __builtin_amdgcn_mfma_f32_16x16x32_f16(w, ha[kk], a, 0,0,0);
    b = __builtin_amdgcn_mfma_f32_16x16x32_f16(w, hb[kk], b, 0,0,0);
  }
  if (g == 0){
    f32x4 oa, ob;
    #pragma unroll
    for (int j=0;j<4;j++){ oa[j] = fast_sigmoid(a[j]); ob[j] = fast_sigmoid(b[j]); }
    *(f32x4*)(out + (size_t)(R0 + nlo)*4)      = oa;
    *(f32x4*)(out + (size_t)(R0 + 16 + nlo)*4) = ob;
  }
}

extern "C" void kernel_launch(void* const* d_in, const int* in_sizes, int n_in,
                              void* d_out, int out_size, void* d_ws, size_t ws_size,
                              hipStream_t stream) {
  const float* latent  = (const float*)d_in[0];
  const int*   raw_pos = (const int*)d_in[1];
  const float* control = (const float*)d_in[2];
  const float* W1 = (const float*)d_in[3];
  const float* b1 = (const float*)d_in[4];
  const float* W2 = (const float*)d_in[5];
  const float* b2 = (const float*)d_in[6];
  const float* W3 = (const float*)d_in[7];
  const float* b3 = (const float*)d_in[8];
  const float* W4 = (const float*)d_in[9];
  const float* b4 = (const float*)d_in[10];
  unsigned short* packed = (unsigned short*)d_ws;

  prepack_kernel<<<12, 256, 0, stream>>>(W1,b1,W2,b2,W3,b3,W4,b4,packed);
  decoder_kernel<<<NTILES, 512, 0, stream>>>(latent, raw_pos, control, packed, (float*)d_out);
}

// Round 8
// 108.310 us; speedup vs baseline: 1.1669x; 1.1669x over previous
//
#include <hip/hip_runtime.h>
#include <hip/hip_fp16.h>

typedef __attribute__((ext_vector_type(8))) _Float16 half8;
typedef __attribute__((ext_vector_type(4))) float f32x4;
typedef __attribute__((ext_vector_type(4))) unsigned int uint4v;

#define HGT 2048
#define WID 2048
#define NPTS 1000000
#define NTILES 3907           // ceil(1e6 / 256 points per block)
#define WBYTES 44096          // 42 frags * 1024 B + 1088 B biases
#define BIAS_OFF 43008

// Feature-slot permutation maps: producer c-slot feeding k-slot k (register-renaming transpose).
__device__ __host__ inline int c64map(int k){   // 64-feature producer
  return 16*(k>>5) + 32*((k&7)>>2) + 4*((k>>3)&3) + (k&3);
}
__device__ __host__ inline int c128map(int k){  // 128-feature producer
  return 16*(k>>5) + 64*((k&7)>>2) + 4*((k>>3)&3) + (k&3);
}

// ---------------- prepack: weights -> f16 A-fragment order in d_ws ----------------
__global__ void prepack_kernel(const float* __restrict__ W1, const float* __restrict__ b1,
                               const float* __restrict__ W2, const float* __restrict__ b2,
                               const float* __restrict__ W3, const float* __restrict__ b3,
                               const float* __restrict__ W4, const float* __restrict__ b4,
                               unsigned short* __restrict__ packed){
  int tid = blockIdx.x*256 + threadIdx.x;
  if (tid < 42*64) {
    int f = tid >> 6, l = tid & 63;
    int fr = l & 15, kg = l >> 4;
    int layer, mt, kk;
    if (f < 8)       { layer=1; mt=f>>1;      kk=f&1; }
    else if (f < 24) { layer=2; mt=(f-8)>>1;  kk=(f-8)&1; }
    else if (f < 40) { layer=3; mt=(f-24)>>2; kk=(f-24)&3; }
    else             { layer=4; mt=0;         kk=f-40; }
    unsigned short v16[8];
    #pragma unroll
    for (int e=0;e<8;e++){
      int k = kk*32 + kg*8 + e;
      int fout = mt*16 + fr;
      float v = 0.0f;
      if (layer==1) {
        if (k < 36)      { v = W1[((k>>2)*12 + (k&3))*64 + fout]; }
        else if (k < 42) { float s=0.f; for (int p=0;p<9;p++) s += W1[(p*12+4+(k-36))*64 + fout]; v=s; }
        else if (k < 44) { float s=0.f; for (int p=0;p<9;p++) s += W1[(p*12+10+(k-42))*64 + fout]; v=s; }
      } else if (layer==2) { v = W2[c64map(k)*128 + fout]; }
      else if (layer==3)   { v = W3[c128map(k)*64 + fout]; }
      else                 { v = (fr < 4) ? W4[c64map(k)*4 + fr] : 0.0f; }
      v16[e] = __half_as_ushort(__float2half(v));
    }
    unsigned short* dst = packed + (size_t)f*512 + (size_t)l*8;
    #pragma unroll
    for (int e=0;e<8;e++) dst[e] = v16[e];
  }
  int bt = tid - 42*64;
  if (bt >= 0 && bt < 272) {
    float v;
    if (bt < 64)       v = b1[bt];
    else if (bt < 192) v = b2[bt-64];
    else if (bt < 256) v = b3[bt-192];
    else               v = (bt-256 < 4) ? b4[bt-256] : 0.0f;
    ((float*)((char*)packed + BIAS_OFF))[bt] = v;
  }
}

// ---------------- helpers ----------------
__device__ inline unsigned pkf(float a, float b){
  return __builtin_bit_cast(unsigned, __builtin_amdgcn_cvt_pkrtz(a, b));
}
// tanh-form GELU, all guaranteed-single-instr ops (7 VALU/elem):
// gelu(x) = x - x*r,  r = rcp(1 + 2^z),  z = x*(2.3021164 + 0.10294913 x^2).
// x->+inf: 2^z=inf -> r=0 -> x.  x->-inf: 2^z=0 -> r=1 -> 0.  No clamps/branches.
__device__ inline float gelu1(float x){
  const float x2 = x*x;
  const float z  = x * __builtin_fmaf(0.10294913f, x2, 2.3021164f);
  const float t  = __builtin_amdgcn_exp2f(z);
  const float r  = __builtin_amdgcn_rcpf(t + 1.0f);
  return __builtin_fmaf(-x, r, x);
}
__device__ inline unsigned gelu2_v(float a, float b){
  return pkf(gelu1(a), gelu1(b));
}
__device__ inline float fast_sigmoid(float x){
  return __builtin_amdgcn_rcpf(1.0f + __builtin_amdgcn_exp2f(-1.442695041f*x));
}

// One layer for TWO 16-point groups sharing each weight-frag read (J=2).
// C-in = bias (free bias add). GELU output written DIRECTLY into the next
// layer's K-fragment slot: producer mt -> out[mt%DKT][(mt/DKT)*2 + j].
// All indices compile-time after unroll (no scratch).
template<int MT,int KT,int DKT,int FB,int BO>
__device__ inline void layer2(const half8* __restrict__ Wfrag, const float* __restrict__ bias,
                              const uint4v* ia, const uint4v* ib,
                              uint4v* oa, uint4v* ob, int lane, int g){
  #pragma unroll
  for (int mt=0; mt<MT; mt++){
    const f32x4 bv = *(const f32x4*)(bias + BO + mt*16 + g*4);
    f32x4 a = bv, b = bv;
    #pragma unroll
    for (int kk=0; kk<KT; kk++){
      const half8 w = Wfrag[(FB + mt*KT + kk)*64 + lane];
      a = __builtin_amdgcn_mfma_f32_16x16x32_f16(w, __builtin_bit_cast(half8, ia[kk]), a, 0,0,0);
      b = __builtin_amdgcn_mfma_f32_16x16x32_f16(w, __builtin_bit_cast(half8, ib[kk]), b, 0,0,0);
    }
    oa[mt%DKT][(mt/DKT)*2+0] = gelu2_v(a[0], a[1]);
    oa[mt%DKT][(mt/DKT)*2+1] = gelu2_v(a[2], a[3]);
    ob[mt%DKT][(mt/DKT)*2+0] = gelu2_v(b[0], b[1]);
    ob[mt%DKT][(mt/DKT)*2+1] = gelu2_v(b[2], b[3]);
  }
}

// ---------------- main fused kernel: registers-only dataflow ----------------
__global__ __launch_bounds__(512, 6)
void decoder_kernel(const float* __restrict__ latent, const int* __restrict__ raw_pos,
                    const float* __restrict__ control, const unsigned short* __restrict__ packed,
                    float* __restrict__ out){
  __shared__ __attribute__((aligned(16))) char smem[WBYTES];
  const int tid = threadIdx.x;
  {
    const f32x4* src = (const f32x4*)packed;
    f32x4* dst = (f32x4*)smem;
    for (int i = tid; i < WBYTES/16; i += 512) dst[i] = src[i];
  }
  __syncthreads();

  const half8* Wfrag = (const half8*)smem;
  const float* bias  = (const float*)(smem + BIAS_OFF);
  const int wave = tid >> 6, lane = tid & 63;
  const int nlo = lane & 15, g = lane >> 4;
  // per-lane gather offsets for pixels 2g, 2g+1 (dx = p%3-1, dy = p/3-1)
  const int pA = g*2, pB = g*2+1;
  const int qA = (pA>=3) + (pA>=6), qB = (pB>=3) + (pB>=6);
  const int dyA = qA-1, dxA = pA-3*qA-1;
  const int dyB = qB-1, dxB = pB-3*qB-1;

  const int tile = blockIdx.x;
  const int R0 = tile*256 + wave*32;
  if (R0 >= NPTS) return;

  // ---------- build L1 B-frags for two point groups, per-lane direct gather ----------
  uint4v bx0[2], bx1[2];
  #pragma unroll
  for (int jj=0; jj<2; jj++){
    const int prow = R0 + jj*16 + nlo;
    const int2 xy = ((const int2*)raw_pos)[prow];
    const int exA = min(max(xy.x + dxA, 0), WID-1);
    const int eyA = min(max(xy.y + dyA, 0), HGT-1);
    const int exB = min(max(xy.x + dxB, 0), WID-1);
    const int eyB = min(max(xy.y + dyB, 0), HGT-1);
    const f32x4 lA = *(const f32x4*)(latent + ((size_t)eyA*WID + exA)*4);
    const f32x4 lB = *(const f32x4*)(latent + ((size_t)eyB*WID + exB)*4);
    uint4v f0;
    f0.x = pkf(lA[0], lA[1]); f0.y = pkf(lA[2], lA[3]);
    f0.z = pkf(lB[0], lB[1]); f0.w = pkf(lB[2], lB[3]);

    const float xs = (float)xy.x * (1.0f/WID), ys = (float)xy.y * (1.0f/HGT);
    const float sx = __builtin_amdgcn_sinf(xs), cx = __builtin_amdgcn_cosf(xs);
    const float sy = __builtin_amdgcn_sinf(ys), cy = __builtin_amdgcn_cosf(ys);
    uint4v f1; f1.x = 0u; f1.y = 0u; f1.z = 0u; f1.w = 0u;
    if (g == 0){
      const int ex8 = min(xy.x + 1, WID-1), ey8 = min(xy.y + 1, HGT-1);
      const f32x4 l8 = *(const f32x4*)(latent + ((size_t)ey8*WID + ex8)*4);
      f1.x = pkf(l8[0], l8[1]); f1.y = pkf(l8[2], l8[3]);
      f1.z = pkf(xs, ys); f1.w = pkf(sx, cx);
    } else if (g == 1){
      const float2 ct = ((const float2*)control)[prow];
      f1.x = pkf(sy, cy); f1.y = pkf(ct.x, ct.y);
    }
    if (jj == 0){ bx0[0] = f0; bx0[1] = f1; }
    else        { bx1[0] = f0; bx1[1] = f1; }
  }

  // ---------- MLP chain, activations live entirely in registers ----------
  uint4v h1a[2], h1b[2], h2a[4], h2b[4], h3a[2], h3b[2];
  layer2<4,2,2, 0,  0>(Wfrag, bias, bx0, bx1, h1a, h1b, lane, g);   // L1: 64->64
  layer2<8,2,4, 8, 64>(Wfrag, bias, h1a, h1b, h2a, h2b, lane, g);   // L2: 64->128
  layer2<4,4,2,24,192>(Wfrag, bias, h2a, h2b, h3a, h3b, lane, g);   // L3: 128->64

  // ---------- L4: 64->4 + sigmoid ----------
  const f32x4 bv4 = *(const f32x4*)(bias + 256 + g*4);
  f32x4 a = bv4, b = bv4;
  #pragma unroll
  for (int kk=0; kk<2; kk++){
    const half8 w = Wfrag[(40+kk)*64 + lane];
    a = __builtin_amdgcn_mfma_f32_16x16x32_f16(w, __builtin_bit_cast(half8, h3a[kk]), a, 0,0,0);
    b = __builtin_amdgcn_mfma_f32_16x16x32_f16(w, __builtin_bit_cast(half8, h3b[kk]), b, 0,0,0);
  }
  if (g == 0){
    f32x4 oa, ob;
    #pragma unroll
    for (int j=0;j<4;j++){ oa[j] = fast_sigmoid(a[j]); ob[j] = fast_sigmoid(b[j]); }
    *(f32x4*)(out + (size_t)(R0 + nlo)*4)      = oa;
    *(f32x4*)(out + (size_t)(R0 + 16 + nlo)*4) = ob;
  }
}

extern "C" void kernel_launch(void* const* d_in, const int* in_sizes, int n_in,
                              void* d_out, int out_size, void* d_ws, size_t ws_size,
                              hipStream_t stream) {
  const float* latent  = (const float*)d_in[0];
  const int*   raw_pos = (const int*)d_in[1];
  const float* control = (const float*)d_in[2];
  const float* W1 = (const float*)d_in[3];
  const float* b1 = (const float*)d_in[4];
  const float* W2 = (const float*)d_in[5];
  const float* b2 = (const float*)d_in[6];
  const float* W3 = (const float*)d_in[7];
  const float* b3 = (const float*)d_in[8];
  const float* W4 = (const float*)d_in[9];
  const float* b4 = (const float*)d_in[10];
  unsigned short* packed = (unsigned short*)d_ws;

  prepack_kernel<<<12, 256, 0, stream>>>(W1,b1,W2,b2,W3,b3,W4,b4,packed);
  decoder_kernel<<<NTILES, 512, 0, stream>>>(latent, raw_pos, control, packed, (float*)d_out);
}